// Round 1
// baseline (229.797 us; speedup 1.0000x reference)
//
#include <hip/hip_runtime.h>
#include <hip/hip_bf16.h>

// Problem constants (B,G,D,H,K,V) = (4, 2048, 128, 8, 16, 16)
#define BB 4
#define GG 2048
#define DD 128
#define HH 8
#define KK 16
#define VV 16
#define BH 32          // B*H

typedef __attribute__((ext_vector_type(8))) short bfrag8;   // 8 bf16 = 4 VGPRs (MFMA A/B frag)
typedef __attribute__((ext_vector_type(4))) float f32x4;    // MFMA C/D frag
typedef unsigned short u16;
typedef unsigned int   u32;
typedef unsigned long long u64;

// 0.25 (=1/sqrt(16) compat factor) * log2(e): folded into Q so softmax uses exp2 directly.
#define QSCALE 0.36067376022224085f

// ws layout (bytes): needs 6.5 MB total
#define OFF_Q 0u          // bf16 [BH][G][16]  (scaled)   2 MB
#define OFF_K (2u << 20)  // bf16 [BH][G][16]             2 MB
#define OFF_V (4u << 20)  // bf16 [BH][16][G]  (V^T)      2 MB
#define OFF_M (6u << 20)  // u64  [G][G/64] mask bits   512 KB

static __device__ __forceinline__ u16 f2bf(float x) {
  __hip_bfloat16 b = __float2bfloat16(x);
  u16 r; __builtin_memcpy(&r, &b, 2); return r;
}
static __device__ __forceinline__ u32 pack2bf(float a, float b) {
  return (u32)f2bf(a) | ((u32)f2bf(b) << 16);
}

// ---------------------------------------------------------------------------
// Kernel 1: projections q,k,v = h @ W per head. One thread per (b,h,g) row.
// Weights are wave-uniform (a wave never spans two bh since 2048 % 64 == 0),
// so W loads broadcast from L1/L2. Q is pre-scaled by 0.25*log2e.
// ---------------------------------------------------------------------------
__global__ __launch_bounds__(256) void proj_kernel(
    const float* __restrict__ h, const float* __restrict__ WQ,
    const float* __restrict__ WK, const float* __restrict__ WV,
    u16* __restrict__ Qbf, u16* __restrict__ Kbf, u16* __restrict__ Vt)
{
  int idx = blockIdx.x * 256 + threadIdx.x;   // [0, BH*G)
  int g  = idx & (GG - 1);
  int bh = idx >> 11;
  int b  = bh >> 3;
  int hh = bh & (HH - 1);
  const float* hrow = h + ((size_t)b * GG + g) * DD;
  const float* wq = WQ + (size_t)hh * DD * KK;
  const float* wk = WK + (size_t)hh * DD * KK;
  const float* wv = WV + (size_t)hh * DD * VV;

  float aq[16], ak[16], av[16];
  #pragma unroll
  for (int i = 0; i < 16; ++i) { aq[i] = 0.f; ak[i] = 0.f; av[i] = 0.f; }

  for (int d4 = 0; d4 < DD / 4; ++d4) {
    float4 hv = *(const float4*)(hrow + d4 * 4);
    float hs[4] = {hv.x, hv.y, hv.z, hv.w};
    #pragma unroll
    for (int dd = 0; dd < 4; ++dd) {
      int d = d4 * 4 + dd;
      #pragma unroll
      for (int q4 = 0; q4 < 4; ++q4) {
        float4 a = *(const float4*)(wq + d * 16 + q4 * 4);
        float4 c = *(const float4*)(wk + d * 16 + q4 * 4);
        float4 e = *(const float4*)(wv + d * 16 + q4 * 4);
        aq[q4*4+0] += hs[dd] * a.x; aq[q4*4+1] += hs[dd] * a.y;
        aq[q4*4+2] += hs[dd] * a.z; aq[q4*4+3] += hs[dd] * a.w;
        ak[q4*4+0] += hs[dd] * c.x; ak[q4*4+1] += hs[dd] * c.y;
        ak[q4*4+2] += hs[dd] * c.z; ak[q4*4+3] += hs[dd] * c.w;
        av[q4*4+0] += hs[dd] * e.x; av[q4*4+1] += hs[dd] * e.y;
        av[q4*4+2] += hs[dd] * e.z; av[q4*4+3] += hs[dd] * e.w;
      }
    }
  }

  u16 qr[16], kr[16];
  #pragma unroll
  for (int i = 0; i < 16; ++i) { qr[i] = f2bf(aq[i] * QSCALE); kr[i] = f2bf(ak[i]); }
  __builtin_memcpy(Qbf + (size_t)idx * 16, qr, 32);
  __builtin_memcpy(Kbf + (size_t)idx * 16, kr, 32);
  #pragma unroll
  for (int i = 0; i < 16; ++i)
    Vt[((size_t)bh * 16 + i) * GG + g] = f2bf(av[i]);   // transposed store
}

// ---------------------------------------------------------------------------
// Kernel 2: mask[G,G] int32 -> bit mask, 1 bit per element via wave ballot.
// bit i of word w of row q == (mask[q][w*64+i] > 0)
// ---------------------------------------------------------------------------
__global__ __launch_bounds__(256) void mask_kernel(
    const int* __restrict__ mask, u64* __restrict__ mbits)
{
  int idx = blockIdx.x * 256 + threadIdx.x;   // over G*G
  u64 bal = __ballot(mask[idx] > 0);
  if ((threadIdx.x & 63) == 0) mbits[idx >> 6] = bal;
}

// ---------------------------------------------------------------------------
// Kernel 3: flash attention. Block = 4 waves, each wave owns 16 q-rows of one
// (b,h). S^T = K·Q^T per 16-key MFMA tile so each lane's scores share one q
// column -> per-lane denominator accumulation, no in-loop cross-lane ops, no
// max subtraction (scores bounded ~|15|, exp2 safe in fp32), and P packs into
// contiguous ds_write_b64. Per-wave private P buffer -> zero barriers.
// ---------------------------------------------------------------------------
__global__ __launch_bounds__(256, 4) void attn_kernel(
    const u16* __restrict__ Qbf, const u16* __restrict__ Kbf,
    const u16* __restrict__ Vt, const u64* __restrict__ mbits,
    float* __restrict__ out)
{
  __shared__ __align__(16) u16 Plds[4][16][72];  // per-wave [q 16][key 64 pad->72]
  const int tid  = threadIdx.x;
  const int wave = tid >> 6;
  const int lane = tid & 63;
  const int col  = lane & 15;   // C-layout column (= q index in S^T orientation)
  const int quad = lane >> 4;
  const int blk  = blockIdx.x;
  const int bh   = blk >> 5;            // 32 q-blocks of 64 rows per bh
  const int qbase = (blk & 31) * 64 + wave * 16;

  // Q as B-fragment: B[k=dim][n=q]: lane reads Q[qbase+col][quad*8..+7]; dims 16..31 are zero pad.
  bfrag8 qfrag = {0,0,0,0,0,0,0,0};
  if (quad < 2)
    __builtin_memcpy(&qfrag, Qbf + ((size_t)bh * GG + qbase + col) * 16 + quad * 8, 16);

  f32x4 acc = {0.f, 0.f, 0.f, 0.f};
  const f32x4 zero4 = {0.f, 0.f, 0.f, 0.f};
  float lsum = 0.f;  // per-lane partial softmax denominator for q = col
  const u64* mrow = mbits + (size_t)(qbase + col) * (GG / 64);
  const u16* Kb = Kbf + (size_t)bh * GG * 16;
  const u16* Vb = Vt + (size_t)bh * 16 * GG + (size_t)col * GG;  // row col = vdim
  u16 (*Pw)[72] = Plds[wave];

  for (int kt = 0; kt < GG / 64; ++kt) {
    const int kbase = kt * 64;

    // 4 S^T MFMAs: D[key][q] = K-tile · Q^T
    f32x4 s[4];
    #pragma unroll
    for (int t = 0; t < 4; ++t) {
      bfrag8 kf = {0,0,0,0,0,0,0,0};  // A[m=key][k=dim], dims 16..31 zero
      if (quad < 2)
        __builtin_memcpy(&kf, Kb + (size_t)(kbase + t * 16 + col) * 16 + quad * 8, 16);
      s[t] = __builtin_amdgcn_mfma_f32_16x16x32_bf16(kf, qfrag, zero4, 0, 0, 0);
    }

    // mask word for this lane's q row, pre-shifted so bit (t*16 + r) tests key
    // kbase + t*16 + quad*4 + r
    u64 w64 = mrow[kt] >> (quad * 4);
    u32 mlo = (u32)w64;
    u32 mhi = (u32)(w64 >> 32);

    #pragma unroll
    for (int t = 0; t < 4; ++t) {
      u32 mw = (t < 2) ? mlo : mhi;
      const int sb = (t & 1) * 16;
      float p[4];
      #pragma unroll
      for (int r = 0; r < 4; ++r) {
        float pv = exp2f(s[t][r]);                 // Q pre-scaled by 0.25*log2e
        p[r] = ((mw >> (sb + r)) & 1u) ? 0.f : pv; // masked -> exact 0
      }
      lsum += (p[0] + p[1]) + (p[2] + p[3]);
      // lane's 4 p's are adjacent keys (quad*4+r) of row q=col -> one b64 write
      u64 wl = (u64)pack2bf(p[0], p[1]) | ((u64)pack2bf(p[2], p[3]) << 32);
      __builtin_memcpy(&Pw[col][t * 16 + quad * 4], &wl, 8);
    }

    // O += P·V : A[m=q][k=key] from LDS (contiguous b128), B[k=key][n=vdim] from V^T
    #pragma unroll
    for (int hf = 0; hf < 2; ++hf) {
      bfrag8 pf, vf;
      __builtin_memcpy(&pf, &Pw[col][hf * 32 + quad * 8], 16);
      __builtin_memcpy(&vf, Vb + kbase + hf * 32 + quad * 8, 16);
      acc = __builtin_amdgcn_mfma_f32_16x16x32_bf16(pf, vf, acc, 0, 0, 0);
    }
  }

  // Denominator: lanes with same col (4 quads) partition the key space.
  float l = lsum;
  l += __shfl_xor(l, 16, 64);
  l += __shfl_xor(l, 32, 64);
  // O C-layout: lane holds rows quad*4+r, column col=vdim. Need l of row q=quad*4+r:
  // lanes 0..15 hold the reduced l for q=lane.
  #pragma unroll
  for (int r = 0; r < 4; ++r) {
    float lq = __shfl(l, quad * 4 + r, 64);
    float rl = (lq > 0.f) ? (1.f / lq) : 0.f;   // all-masked row -> 0 (matches ref)
    out[((size_t)bh * GG + qbase + quad * 4 + r) * 16 + col] = acc[r] * rl;
  }
}

// ---------------------------------------------------------------------------
extern "C" void kernel_launch(void* const* d_in, const int* in_sizes, int n_in,
                              void* d_out, int out_size, void* d_ws, size_t ws_size,
                              hipStream_t stream) {
  const float* h    = (const float*)d_in[0];
  const int*   mask = (const int*)d_in[1];
  const float* WQ   = (const float*)d_in[2];
  const float* WK   = (const float*)d_in[3];
  const float* WV   = (const float*)d_in[4];
  float* out = (float*)d_out;
  char* ws = (char*)d_ws;     // needs >= 6.5 MB
  u16* Qbf = (u16*)(ws + OFF_Q);
  u16* Kbf = (u16*)(ws + OFF_K);
  u16* Vt  = (u16*)(ws + OFF_V);
  u64* mbits = (u64*)(ws + OFF_M);

  hipLaunchKernelGGL(proj_kernel, dim3(BH * GG / 256), dim3(256), 0, stream,
                     h, WQ, WK, WV, Qbf, Kbf, Vt);
  hipLaunchKernelGGL(mask_kernel, dim3(GG * GG / 256), dim3(256), 0, stream,
                     mask, mbits);
  hipLaunchKernelGGL(attn_kernel, dim3(BH * (GG / 64)), dim3(256), 0, stream,
                     Qbf, Kbf, Vt, mbits, out);
}

// Round 2
// 154.338 us; speedup vs baseline: 1.4889x; 1.4889x over previous
//
#include <hip/hip_runtime.h>
#include <hip/hip_bf16.h>

// Problem constants (B,G,D,H,K,V) = (4, 2048, 128, 8, 16, 16)
#define BB 4
#define GG 2048
#define DD 128
#define HH 8
#define KK 16
#define VV 16
#define BH 32          // B*H
#define HTOT (BB*GG*DD)      // 1,048,576 h elements
#define WTOT (HH*48*DD)      // 49,152 packed weight elements

typedef __attribute__((ext_vector_type(8))) short bfrag8;   // 8 bf16 = 4 VGPRs (MFMA A/B frag)
typedef __attribute__((ext_vector_type(4))) float f32x4;    // MFMA C/D frag
typedef unsigned short u16;
typedef unsigned int   u32;
typedef unsigned long long u64;

// 0.25 (=1/sqrt(16) compat factor) * log2(e): folded into W_Q so softmax uses exp2.
#define QSCALE 0.36067376022224085f

// ws layout (bytes): ~8.6 MB total
#define OFF_Q  0u           // bf16 [BH][G][16]  (scaled)   2 MB
#define OFF_K  (2u << 20)   // bf16 [BH][G][16]             2 MB
#define OFF_V  (4u << 20)   // bf16 [BH][16][G]  (V^T)      2 MB
#define OFF_M  (6u << 20)   // u64  [G][G/64] mask bits   512 KB
#define OFF_HB 6815744u     // bf16 h [B][G][128]           2 MB
#define OFF_WC 8912896u     // bf16 Wc [H][48][128]        96 KB

static __device__ __forceinline__ u16 f2bf(float x) {
  __hip_bfloat16 b = __float2bfloat16(x);
  u16 r; __builtin_memcpy(&r, &b, 2); return r;
}
static __device__ __forceinline__ u32 pack2bf(float a, float b) {
  return (u32)f2bf(a) | ((u32)f2bf(b) << 16);
}

// ---------------------------------------------------------------------------
// Kernel 1: convert h -> bf16, and W_Q/W_K/W_V -> packed bf16 Wc[h][n=48][d=128]
// (k-contiguous so MFMA B-fragments load as 16B rows). QSCALE folded into Q cols.
// ---------------------------------------------------------------------------
__global__ __launch_bounds__(256) void convert_kernel(
    const float* __restrict__ h, const float* __restrict__ WQ,
    const float* __restrict__ WK, const float* __restrict__ WV,
    u32* __restrict__ hbf2, u16* __restrict__ Wc)
{
  int idx = blockIdx.x * 256 + threadIdx.x;
  if (idx < HTOT / 2) {
    float2 v = ((const float2*)h)[idx];
    hbf2[idx] = pack2bf(v.x, v.y);
  } else {
    int j = idx - HTOT / 2;            // [0, WTOT)
    int hh = j / (48 * DD);
    int r  = j % (48 * DD);
    int n  = r / DD;
    int d  = r % DD;
    float val;
    if (n < 16)      val = WQ[((size_t)hh * DD + d) * 16 + n] * QSCALE;
    else if (n < 32) val = WK[((size_t)hh * DD + d) * 16 + (n - 16)];
    else             val = WV[((size_t)hh * DD + d) * 16 + (n - 32)];
    Wc[j] = f2bf(val);
  }
}

// ---------------------------------------------------------------------------
// Kernel 2: MFMA projection. One wave per (bh, 64-row g-tile):
// [64 x 128] x [128 x 48] via 4 m-tiles x 3 n-tiles x 4 k-steps = 48 MFMAs.
// A[m=lane&15][k=quad*8+j] from h_bf (16B rows); B from Wc (16B rows).
// C layout col=lane&15 row=quad*4+r -> scalar bf16 stores to Q/K/V^T.
// ---------------------------------------------------------------------------
__global__ __launch_bounds__(64) void proj_mfma(
    const u16* __restrict__ hbf, const u16* __restrict__ Wc,
    u16* __restrict__ Qbf, u16* __restrict__ Kbf, u16* __restrict__ Vt)
{
  const int bh = blockIdx.x >> 5;
  const int gt = blockIdx.x & 31;
  const int b  = bh >> 3;
  const int hh = bh & (HH - 1);
  const int lane = threadIdx.x;
  const int col  = lane & 15;
  const int quad = lane >> 4;
  const int g0 = gt * 64;

  const u16* hb = hbf + (size_t)b * GG * DD;
  const u16* W  = Wc + (size_t)hh * 48 * DD;

  f32x4 acc[4][3];
  #pragma unroll
  for (int mt = 0; mt < 4; ++mt)
    #pragma unroll
    for (int nt = 0; nt < 3; ++nt)
      acc[mt][nt] = (f32x4){0.f, 0.f, 0.f, 0.f};

  #pragma unroll
  for (int s = 0; s < 4; ++s) {     // k-steps of 32 dims
    bfrag8 a[4], bf[3];
    #pragma unroll
    for (int mt = 0; mt < 4; ++mt)
      __builtin_memcpy(&a[mt], hb + (size_t)(g0 + mt * 16 + col) * DD + s * 32 + quad * 8, 16);
    #pragma unroll
    for (int nt = 0; nt < 3; ++nt)
      __builtin_memcpy(&bf[nt], W + (size_t)(nt * 16 + col) * DD + s * 32 + quad * 8, 16);
    #pragma unroll
    for (int mt = 0; mt < 4; ++mt)
      #pragma unroll
      for (int nt = 0; nt < 3; ++nt)
        acc[mt][nt] = __builtin_amdgcn_mfma_f32_16x16x32_bf16(a[mt], bf[nt], acc[mt][nt], 0, 0, 0);
  }

  #pragma unroll
  for (int mt = 0; mt < 4; ++mt) {
    #pragma unroll
    for (int r = 0; r < 4; ++r) {
      int g = g0 + mt * 16 + quad * 4 + r;
      Qbf[((size_t)bh * GG + g) * 16 + col] = f2bf(acc[mt][0][r]);
      Kbf[((size_t)bh * GG + g) * 16 + col] = f2bf(acc[mt][1][r]);
      Vt[((size_t)bh * 16 + col) * GG + g]  = f2bf(acc[mt][2][r]);
    }
  }
}

// ---------------------------------------------------------------------------
// Kernel 3: mask[G,G] int32 -> bit mask via wave ballot.
// ---------------------------------------------------------------------------
__global__ __launch_bounds__(256) void mask_kernel(
    const int* __restrict__ mask, u64* __restrict__ mbits)
{
  int idx = blockIdx.x * 256 + threadIdx.x;
  u64 bal = __ballot(mask[idx] > 0);
  if ((threadIdx.x & 63) == 0) mbits[idx >> 6] = bal;
}

// ---------------------------------------------------------------------------
// Kernel 4: flash attention (unchanged from round 1 — passed at absmax 0.031).
// S^T = K·Q^T per 16-key tile: per-lane denominator, no max-subtraction,
// P packs to contiguous ds_write_b64; per-wave private P buffer, no barriers.
// ---------------------------------------------------------------------------
__global__ __launch_bounds__(256, 4) void attn_kernel(
    const u16* __restrict__ Qbf, const u16* __restrict__ Kbf,
    const u16* __restrict__ Vt, const u64* __restrict__ mbits,
    float* __restrict__ out)
{
  __shared__ __align__(16) u16 Plds[4][16][72];
  const int tid  = threadIdx.x;
  const int wave = tid >> 6;
  const int lane = tid & 63;
  const int col  = lane & 15;
  const int quad = lane >> 4;
  const int blk  = blockIdx.x;
  const int bh   = blk >> 5;
  const int qbase = (blk & 31) * 64 + wave * 16;

  bfrag8 qfrag = {0,0,0,0,0,0,0,0};
  if (quad < 2)
    __builtin_memcpy(&qfrag, Qbf + ((size_t)bh * GG + qbase + col) * 16 + quad * 8, 16);

  f32x4 acc = {0.f, 0.f, 0.f, 0.f};
  const f32x4 zero4 = {0.f, 0.f, 0.f, 0.f};
  float lsum = 0.f;
  const u64* mrow = mbits + (size_t)(qbase + col) * (GG / 64);
  const u16* Kb = Kbf + (size_t)bh * GG * 16;
  const u16* Vb = Vt + (size_t)bh * 16 * GG + (size_t)col * GG;
  u16 (*Pw)[72] = Plds[wave];

  for (int kt = 0; kt < GG / 64; ++kt) {
    const int kbase = kt * 64;

    f32x4 s[4];
    #pragma unroll
    for (int t = 0; t < 4; ++t) {
      bfrag8 kf = {0,0,0,0,0,0,0,0};
      if (quad < 2)
        __builtin_memcpy(&kf, Kb + (size_t)(kbase + t * 16 + col) * 16 + quad * 8, 16);
      s[t] = __builtin_amdgcn_mfma_f32_16x16x32_bf16(kf, qfrag, zero4, 0, 0, 0);
    }

    u64 w64 = mrow[kt] >> (quad * 4);
    u32 mlo = (u32)w64;
    u32 mhi = (u32)(w64 >> 32);

    #pragma unroll
    for (int t = 0; t < 4; ++t) {
      u32 mw = (t < 2) ? mlo : mhi;
      const int sb = (t & 1) * 16;
      float p[4];
      #pragma unroll
      for (int r = 0; r < 4; ++r) {
        float pv = exp2f(s[t][r]);
        p[r] = ((mw >> (sb + r)) & 1u) ? 0.f : pv;
      }
      lsum += (p[0] + p[1]) + (p[2] + p[3]);
      u64 wl = (u64)pack2bf(p[0], p[1]) | ((u64)pack2bf(p[2], p[3]) << 32);
      __builtin_memcpy(&Pw[col][t * 16 + quad * 4], &wl, 8);
    }

    #pragma unroll
    for (int hf = 0; hf < 2; ++hf) {
      bfrag8 pf, vf;
      __builtin_memcpy(&pf, &Pw[col][hf * 32 + quad * 8], 16);
      __builtin_memcpy(&vf, Vb + kbase + hf * 32 + quad * 8, 16);
      acc = __builtin_amdgcn_mfma_f32_16x16x32_bf16(pf, vf, acc, 0, 0, 0);
    }
  }

  float l = lsum;
  l += __shfl_xor(l, 16, 64);
  l += __shfl_xor(l, 32, 64);
  #pragma unroll
  for (int r = 0; r < 4; ++r) {
    float lq = __shfl(l, quad * 4 + r, 64);
    float rl = (lq > 0.f) ? (1.f / lq) : 0.f;
    out[((size_t)bh * GG + qbase + quad * 4 + r) * 16 + col] = acc[r] * rl;
  }
}

// ---------------------------------------------------------------------------
extern "C" void kernel_launch(void* const* d_in, const int* in_sizes, int n_in,
                              void* d_out, int out_size, void* d_ws, size_t ws_size,
                              hipStream_t stream) {
  const float* h    = (const float*)d_in[0];
  const int*   mask = (const int*)d_in[1];
  const float* WQ   = (const float*)d_in[2];
  const float* WK   = (const float*)d_in[3];
  const float* WV   = (const float*)d_in[4];
  float* out = (float*)d_out;
  char* ws = (char*)d_ws;     // needs >= ~8.6 MB
  u16* Qbf = (u16*)(ws + OFF_Q);
  u16* Kbf = (u16*)(ws + OFF_K);
  u16* Vt  = (u16*)(ws + OFF_V);
  u64* mbits = (u64*)(ws + OFF_M);
  u32* hbf2 = (u32*)(ws + OFF_HB);
  u16* Wc   = (u16*)(ws + OFF_WC);

  hipLaunchKernelGGL(convert_kernel, dim3((HTOT / 2 + WTOT) / 256), dim3(256), 0, stream,
                     h, WQ, WK, WV, hbf2, Wc);
  hipLaunchKernelGGL(proj_mfma, dim3(BH * (GG / 64)), dim3(64), 0, stream,
                     (const u16*)hbf2, Wc, Qbf, Kbf, Vt);
  hipLaunchKernelGGL(mask_kernel, dim3(GG * GG / 256), dim3(256), 0, stream,
                     mask, mbits);
  hipLaunchKernelGGL(attn_kernel, dim3(BH * (GG / 64)), dim3(256), 0, stream,
                     Qbf, Kbf, Vt, mbits, out);
}

// Round 3
// 150.062 us; speedup vs baseline: 1.5313x; 1.0285x over previous
//
#include <hip/hip_runtime.h>
#include <hip/hip_bf16.h>

// Problem constants (B,G,D,H,K,V) = (4, 2048, 128, 8, 16, 16)
#define GG 2048
#define DD 128
#define HH 8
#define BH 32

typedef __attribute__((ext_vector_type(8))) short bfrag8;   // 8 bf16 (4 VGPRs)
typedef __attribute__((ext_vector_type(4))) float f32x4;    // MFMA C/D frag
typedef unsigned short u16;
typedef unsigned int   u32;
typedef unsigned long long u64;

// 0.25 (=1/sqrt(16)) * log2(e): folded into W_Q so softmax uses raw exp2.
#define QSCALE 0.36067376022224085f

// ws layout: 6.5 MB
#define OFF_Q 0u          // bf16 [BH][G][16] (scaled)  2 MB
#define OFF_K (2u << 20)  // bf16 [BH][G][16]           2 MB
#define OFF_V (4u << 20)  // bf16 [BH][16][G] (V^T)     2 MB
#define OFF_M (6u << 20)  // u64  [G][G/64] mask bits 512 KB

#if __has_builtin(__builtin_amdgcn_exp2f)
#define EXP2F(x) __builtin_amdgcn_exp2f(x)
#else
#define EXP2F(x) exp2f(x)
#endif

static __device__ __forceinline__ u16 f2bf(float x) {          // RNE (cold paths)
  __hip_bfloat16 b = __float2bfloat16(x);
  u16 r; __builtin_memcpy(&r, &b, 2); return r;
}
// hot path: round-half-up truncation pack of 2 floats -> bf16 pair (4 VALU ops).
// p >= 0 and p <= 2^15 here, so +0x8000 can't overflow; exact 0 stays 0.
static __device__ __forceinline__ u32 pack2bf_fast(float a, float b) {
  u32 ai = __builtin_bit_cast(u32, a) + 0x8000u;
  u32 bi = __builtin_bit_cast(u32, b) + 0x8000u;
  return (ai >> 16) | (bi & 0xFFFF0000u);
}

// ---------------------------------------------------------------------------
// Kernel 1 (fused prep): blocks [0,256): MFMA projection with per-block W pack
// into LDS (h converted fp32->bf16 in-registers). blocks [256, 256+16384):
// mask[G,G] int32 -> 1-bit-per-element bitmap via ballot.
// ---------------------------------------------------------------------------
__global__ __launch_bounds__(256) void prep_kernel(
    const float* __restrict__ h, const int* __restrict__ mask,
    const float* __restrict__ WQ, const float* __restrict__ WK,
    const float* __restrict__ WV,
    u16* __restrict__ Qbf, u16* __restrict__ Kbf, u16* __restrict__ Vt,
    u64* __restrict__ mbits)
{
  const int blk = blockIdx.x;
  const int tid = threadIdx.x;

  if (blk >= 256) {               // ---- mask bitmap section ----
    int idx = (blk - 256) * 256 + tid;        // over G*G
    u64 bal = __ballot(mask[idx] > 0);
    if ((tid & 63) == 0) mbits[idx >> 6] = bal;
    return;
  }

  // ---- projection section: 8 blocks per bh, 4 waves/block, 64 g-rows/wave ----
  __shared__ __align__(16) u16 Wl[48 * 136];   // [n=48][d=128 pad 136] bf16
  const int bh = blk >> 3;
  const int b  = bh >> 3;
  const int hh = bh & (HH - 1);

  // cooperative W pack: 3 mats x 2048 fp32 -> Wl[n][d], QSCALE folded into Q cols
  #pragma unroll
  for (int m = 0; m < 3; ++m) {
    const float* W = (m == 0 ? WQ : (m == 1 ? WK : WV)) + (size_t)hh * DD * 16;
    const float sc = (m == 0) ? QSCALE : 1.0f;
    #pragma unroll
    for (int i = 0; i < 2; ++i) {
      int j4 = i * 256 + tid;                  // float4 index in [0,512)
      float4 v = ((const float4*)W)[j4];
      int j = j4 * 4, d = j >> 4, n0 = (m * 16) + (j & 15);
      Wl[(n0 + 0) * 136 + d] = f2bf(v.x * sc);
      Wl[(n0 + 1) * 136 + d] = f2bf(v.y * sc);
      Wl[(n0 + 2) * 136 + d] = f2bf(v.z * sc);
      Wl[(n0 + 3) * 136 + d] = f2bf(v.w * sc);
    }
  }
  __syncthreads();

  const int wave = tid >> 6, lane = tid & 63;
  const int col = lane & 15, quad = lane >> 4;
  const int g0 = ((blk & 7) * 4 + wave) * 64;
  const float* hb = h + (size_t)b * GG * DD;

  f32x4 acc[4][3];
  #pragma unroll
  for (int mt = 0; mt < 4; ++mt)
    #pragma unroll
    for (int nt = 0; nt < 3; ++nt)
      acc[mt][nt] = (f32x4){0.f, 0.f, 0.f, 0.f};

  #pragma unroll
  for (int s = 0; s < 4; ++s) {                // k-steps of 32 dims
    bfrag8 a[4], bw[3];
    #pragma unroll
    for (int mt = 0; mt < 4; ++mt) {           // A: h rows, convert in-reg (RNE)
      const float* src = hb + (size_t)(g0 + mt * 16 + col) * DD + s * 32 + quad * 8;
      float4 x = ((const float4*)src)[0];
      float4 y = ((const float4*)src)[1];
      u32 pk[4] = { (u32)f2bf(x.x) | ((u32)f2bf(x.y) << 16),
                    (u32)f2bf(x.z) | ((u32)f2bf(x.w) << 16),
                    (u32)f2bf(y.x) | ((u32)f2bf(y.y) << 16),
                    (u32)f2bf(y.z) | ((u32)f2bf(y.w) << 16) };
      __builtin_memcpy(&a[mt], pk, 16);
    }
    #pragma unroll
    for (int nt = 0; nt < 3; ++nt)             // B: W cols from LDS, b128 reads
      __builtin_memcpy(&bw[nt], &Wl[(nt * 16 + col) * 136 + s * 32 + quad * 8], 16);
    #pragma unroll
    for (int mt = 0; mt < 4; ++mt)
      #pragma unroll
      for (int nt = 0; nt < 3; ++nt)
        acc[mt][nt] = __builtin_amdgcn_mfma_f32_16x16x32_bf16(a[mt], bw[nt], acc[mt][nt], 0, 0, 0);
  }

  #pragma unroll
  for (int mt = 0; mt < 4; ++mt) {
    #pragma unroll
    for (int r = 0; r < 4; ++r) {
      int g = g0 + mt * 16 + quad * 4 + r;
      Qbf[((size_t)bh * GG + g) * 16 + col] = f2bf(acc[mt][0][r]);
      Kbf[((size_t)bh * GG + g) * 16 + col] = f2bf(acc[mt][1][r]);
      Vt[((size_t)bh * 16 + col) * GG + g]  = f2bf(acc[mt][2][r]);
    }
  }
}

// ---------------------------------------------------------------------------
// Kernel 2: flash attention, 32 q-rows per wave (two 16-q tiles share every
// K-fragment and V-fragment). S^T = K·Q^T -> per-lane denominator, raw
// v_exp_f32, fast P pack, per-wave private P LDS (no barriers).
// ---------------------------------------------------------------------------
__global__ __launch_bounds__(256, 2) void attn_kernel(
    const u16* __restrict__ Qbf, const u16* __restrict__ Kbf,
    const u16* __restrict__ Vt, const u64* __restrict__ mbits,
    float* __restrict__ out)
{
  __shared__ __align__(16) u16 Plds[4][32][72];
  const int tid = threadIdx.x, wave = tid >> 6, lane = tid & 63;
  const int col = lane & 15, quad = lane >> 4;
  const int bh = blockIdx.x >> 4;
  const int qb = (blockIdx.x & 15) * 128 + wave * 32;

  bfrag8 qf0 = {0,0,0,0,0,0,0,0}, qf1 = {0,0,0,0,0,0,0,0};
  if (quad < 2) {
    __builtin_memcpy(&qf0, Qbf + ((size_t)bh * GG + qb + col) * 16 + quad * 8, 16);
    __builtin_memcpy(&qf1, Qbf + ((size_t)bh * GG + qb + 16 + col) * 16 + quad * 8, 16);
  }

  f32x4 acc0 = {0.f,0.f,0.f,0.f}, acc1 = {0.f,0.f,0.f,0.f};
  const f32x4 zero4 = {0.f,0.f,0.f,0.f};
  float ls0 = 0.f, ls1 = 0.f;
  const u64* mr0 = mbits + (size_t)(qb + col) * (GG / 64);
  const u64* mr1 = mr0 + 16 * (GG / 64);
  const u16* Kb = Kbf + (size_t)bh * GG * 16;
  const u16* Vb = Vt + ((size_t)bh * 16 + col) * GG;
  u16 (*Pw)[72] = Plds[wave];

  for (int kt = 0; kt < GG / 64; ++kt) {
    const int kbase = kt * 64;

    f32x4 s0[4], s1[4];
    #pragma unroll
    for (int t = 0; t < 4; ++t) {
      bfrag8 kf = {0,0,0,0,0,0,0,0};
      if (quad < 2)
        __builtin_memcpy(&kf, Kb + (size_t)(kbase + t * 16 + col) * 16 + quad * 8, 16);
      s0[t] = __builtin_amdgcn_mfma_f32_16x16x32_bf16(kf, qf0, zero4, 0, 0, 0);
      s1[t] = __builtin_amdgcn_mfma_f32_16x16x32_bf16(kf, qf1, zero4, 0, 0, 0);
    }

    u64 w0 = mr0[kt] >> (quad * 4);
    u64 w1 = mr1[kt] >> (quad * 4);
    u32 w0lo = (u32)w0, w0hi = (u32)(w0 >> 32);
    u32 w1lo = (u32)w1, w1hi = (u32)(w1 >> 32);

    #pragma unroll
    for (int t = 0; t < 4; ++t) {
      const int sb = (t & 1) * 16;
      u32 m0 = (t < 2) ? w0lo : w0hi;
      u32 m1 = (t < 2) ? w1lo : w1hi;
      float p0[4], p1[4];
      #pragma unroll
      for (int r = 0; r < 4; ++r) {
        float e0 = EXP2F(s0[t][r]);
        float e1 = EXP2F(s1[t][r]);
        p0[r] = ((m0 >> (sb + r)) & 1u) ? 0.f : e0;
        p1[r] = ((m1 >> (sb + r)) & 1u) ? 0.f : e1;
      }
      ls0 += (p0[0] + p0[1]) + (p0[2] + p0[3]);
      ls1 += (p1[0] + p1[1]) + (p1[2] + p1[3]);
      u64 pk0 = (u64)pack2bf_fast(p0[0], p0[1]) | ((u64)pack2bf_fast(p0[2], p0[3]) << 32);
      u64 pk1 = (u64)pack2bf_fast(p1[0], p1[1]) | ((u64)pack2bf_fast(p1[2], p1[3]) << 32);
      __builtin_memcpy(&Pw[col][t * 16 + quad * 4], &pk0, 8);
      __builtin_memcpy(&Pw[16 + col][t * 16 + quad * 4], &pk1, 8);
    }

    #pragma unroll
    for (int hf = 0; hf < 2; ++hf) {
      bfrag8 vf, pf0, pf1;
      __builtin_memcpy(&vf, Vb + kbase + hf * 32 + quad * 8, 16);
      __builtin_memcpy(&pf0, &Pw[col][hf * 32 + quad * 8], 16);
      __builtin_memcpy(&pf1, &Pw[16 + col][hf * 32 + quad * 8], 16);
      acc0 = __builtin_amdgcn_mfma_f32_16x16x32_bf16(pf0, vf, acc0, 0, 0, 0);
      acc1 = __builtin_amdgcn_mfma_f32_16x16x32_bf16(pf1, vf, acc1, 0, 0, 0);
    }
  }

  float l0 = ls0; l0 += __shfl_xor(l0, 16, 64); l0 += __shfl_xor(l0, 32, 64);
  float l1 = ls1; l1 += __shfl_xor(l1, 16, 64); l1 += __shfl_xor(l1, 32, 64);
  #pragma unroll
  for (int r = 0; r < 4; ++r) {
    float a0 = __shfl(l0, quad * 4 + r, 64);
    float r0 = (a0 > 0.f) ? (1.f / a0) : 0.f;
    out[((size_t)bh * GG + qb + quad * 4 + r) * 16 + col] = acc0[r] * r0;
    float a1 = __shfl(l1, quad * 4 + r, 64);
    float r1 = (a1 > 0.f) ? (1.f / a1) : 0.f;
    out[((size_t)bh * GG + qb + 16 + quad * 4 + r) * 16 + col] = acc1[r] * r1;
  }
}

// ---------------------------------------------------------------------------
extern "C" void kernel_launch(void* const* d_in, const int* in_sizes, int n_in,
                              void* d_out, int out_size, void* d_ws, size_t ws_size,
                              hipStream_t stream) {
  const float* h    = (const float*)d_in[0];
  const int*   mask = (const int*)d_in[1];
  const float* WQ   = (const float*)d_in[2];
  const float* WK   = (const float*)d_in[3];
  const float* WV   = (const float*)d_in[4];
  float* out = (float*)d_out;
  char* ws = (char*)d_ws;     // uses 6.5 MB
  u16* Qbf = (u16*)(ws + OFF_Q);
  u16* Kbf = (u16*)(ws + OFF_K);
  u16* Vt  = (u16*)(ws + OFF_V);
  u64* mbits = (u64*)(ws + OFF_M);

  hipLaunchKernelGGL(prep_kernel, dim3(256 + GG * GG / 256), dim3(256), 0, stream,
                     h, mask, WQ, WK, WV, Qbf, Kbf, Vt, mbits);
  hipLaunchKernelGGL(attn_kernel, dim3(BH * (GG / 128)), dim3(256), 0, stream,
                     Qbf, Kbf, Vt, mbits, out);
}